// Round 15
// baseline (1715.916 us; speedup 1.0000x reference)
//
#include <hip/hip_runtime.h>
#include <hip/hip_bf16.h>
#include <math.h>

#define DEVI static __device__ __forceinline__

typedef unsigned short u16;
typedef unsigned int u32;
typedef __bf16 bf16_t;
typedef bf16_t bf16x8 __attribute__((ext_vector_type(8)));
typedef float f32x4 __attribute__((ext_vector_type(4)));

static constexpr int Bb = 16;     // batch
static constexpr int L  = 1024;   // seq len
static constexpr int D  = 1024;   // 2H
static constexpr int KH = 4096;   // heuristic K = 8H

DEVI u16 f2bf(float f) {
  union { float f; u32 u; } v; v.f = f;
  u32 r = v.u + 0x7FFFu + ((v.u >> 16) & 1u);
  return (u16)(r >> 16);
}

DEVI float bf2f(u16 b) {
  union { u32 u; float f; } v; v.u = ((u32)b) << 16;
  return v.f;
}

DEVI void gload16(const void* g, void* l) {
  __builtin_amdgcn_global_load_lds((const __attribute__((address_space(1))) u32*)g,
                                   (__attribute__((address_space(3))) u32*)l,
                                   16, 0, 0);
}

// element-unit XOR swizzle within a 64-wide bf16 LDS row (T2):
DEVI int swz(int row, int col) { return col ^ ((row & 7) << 3); }

// ---------------- split cast: f32 -> hi bf16 + lo bf16 (residual) ----------------
__global__ void k_cast_split(const float* __restrict__ in, u16* __restrict__ hi,
                             u16* __restrict__ lo, int n4) {
  int i = blockIdx.x * blockDim.x + threadIdx.x;
  int stride = gridDim.x * blockDim.x;
  for (; i < n4; i += stride) {
    float4 v = ((const float4*)in)[i];
    ushort4 h, l;
    h.x = f2bf(v.x); h.y = f2bf(v.y); h.z = f2bf(v.z); h.w = f2bf(v.w);
    l.x = f2bf(v.x - bf2f(h.x));
    l.y = f2bf(v.y - bf2f(h.y));
    l.z = f2bf(v.z - bf2f(h.z));
    l.w = f2bf(v.w - bf2f(h.w));
    ((ushort4*)hi)[i] = h;
    ((ushort4*)lo)[i] = l;
  }
}

// ---------------- interleave weights: wcat[2j]=w_r[j], wcat[2j+1]=w_g[j] (bf16) ----------------
__global__ void k_wcat(const float* __restrict__ wr, const float* __restrict__ wg,
                       u16* __restrict__ wcat, int n4) {
  int i = blockIdx.x * blockDim.x + threadIdx.x;
  int stride = gridDim.x * blockDim.x;
  for (; i < n4; i += stride) {
    int j = i >> 10;              // interleaved row (2048)
    int c4 = i & 1023;            // float4 chunk within row (4096/4)
    const float* src = ((j & 1) ? wg : wr) + (size_t)(j >> 1) * 4096 + c4 * 4;
    float4 v = *(const float4*)src;
    ushort4 o;
    o.x = f2bf(v.x); o.y = f2bf(v.y); o.z = f2bf(v.z); o.w = f2bf(v.w);
    ((ushort4*)wcat)[i] = o;
  }
}

// ---------------- features: xy = x*y, xmy = x-y (bf16 in, bf16 out) ----------------
__global__ void k_feat(const u16* __restrict__ x, const u16* __restrict__ y,
                       u16* __restrict__ xy, u16* __restrict__ xmy, int n8) {
  int i = blockIdx.x * blockDim.x + threadIdx.x;
  int stride = gridDim.x * blockDim.x;
  for (; i < n8; i += stride) {
    bf16x8 xv = ((const bf16x8*)x)[i];
    bf16x8 yv = ((const bf16x8*)y)[i];
    bf16x8 p, d;
    #pragma unroll
    for (int j = 0; j < 8; ++j) {
      float xf = (float)xv[j], yf = (float)yv[j];
      p[j] = (bf16_t)(xf * yf);
      d[j] = (bf16_t)(xf - yf);
    }
    ((bf16x8*)xy)[i] = p;
    ((bf16x8*)xmy)[i] = d;
  }
}

// ---------------- transpose (bf16 in, bf16 out): [B][L][D] -> [B][D][L] ----------------
__global__ __launch_bounds__(256)
void k_transpose_bf16(const u16* __restrict__ in, u16* __restrict__ out) {
  __shared__ u16 tile[32][33];
  int b = blockIdx.z;
  int d0 = blockIdx.x * 32;
  int l0 = blockIdx.y * 32;
  const u16* ip = in + (size_t)b * L * D;
  u16* op = out + (size_t)b * L * D;
  int tx = threadIdx.x, ty = threadIdx.y;
  #pragma unroll
  for (int j = 0; j < 4; ++j)
    tile[ty + 8 * j][tx] = ip[(size_t)(l0 + ty + 8 * j) * D + d0 + tx];
  __syncthreads();
  #pragma unroll
  for (int j = 0; j < 4; ++j)
    op[(size_t)(d0 + ty + 8 * j) * L + l0 + tx] = tile[tx][ty + 8 * j];
}

// ---------------- NT GEMM: C[m][n] = sum_k A[m][k] * B[n][k] (PV GEMMs) ----------------
template<int OUT_BF16>
__global__ __launch_bounds__(256, 4)
void k_gemm_nt(const u16* __restrict__ A, const u16* __restrict__ Bm, void* __restrict__ Cv,
               int K, int ldc, size_t sA, size_t sB, size_t sC, int tilesN)
{
  __shared__ __align__(16) u16 As[128 * 64];
  __shared__ __align__(16) u16 Bs[128 * 64];
  const int bx = blockIdx.x;
  const int tm = bx / tilesN, tn = bx % tilesN;
  const int b = blockIdx.y;
  const u16* Ap = A + (size_t)b * sA + (size_t)tm * 128 * K;
  const u16* Bp = Bm + (size_t)b * sB + (size_t)tn * 128 * K;
  const int tid = threadIdx.x;
  const int lane = tid & 63, wv = tid >> 6;
  const int wm = wv >> 1, wn = wv & 1;
  const int srow = tid >> 3;
  const int scol = (tid & 7) * 8;
  const int scolswz = swz(srow, scol);
  f32x4 acc[4][4] = {};
  for (int k0 = 0; k0 < K; k0 += 64) {
    #pragma unroll
    for (int i = 0; i < 4; ++i) {
      int row = i * 32 + srow;
      gload16(Ap + (size_t)row * K + k0 + scolswz, &As[row * 64 + scol]);
    }
    #pragma unroll
    for (int i = 0; i < 4; ++i) {
      int row = i * 32 + srow;
      gload16(Bp + (size_t)row * K + k0 + scolswz, &Bs[row * 64 + scol]);
    }
    __syncthreads();
    const int hi8 = (lane >> 4) * 8;
    #pragma unroll
    for (int kk = 0; kk < 64; kk += 32) {
      bf16x8 af[4], bfv[4];
      #pragma unroll
      for (int m = 0; m < 4; ++m) {
        int rr = wm * 64 + m * 16 + (lane & 15);
        af[m] = *(const bf16x8*)&As[rr * 64 + swz(rr, kk + hi8)];
      }
      #pragma unroll
      for (int n = 0; n < 4; ++n) {
        int rr = wn * 64 + n * 16 + (lane & 15);
        bfv[n] = *(const bf16x8*)&Bs[rr * 64 + swz(rr, kk + hi8)];
      }
      #pragma unroll
      for (int m = 0; m < 4; ++m)
        #pragma unroll
        for (int n = 0; n < 4; ++n)
          acc[m][n] = __builtin_amdgcn_mfma_f32_16x16x32_bf16(af[m], bfv[n], acc[m][n], 0, 0, 0);
    }
    __syncthreads();
  }
  const int rb = tm * 128 + wm * 64 + ((lane >> 4) << 2);
  const int cb = tn * 128 + wn * 64 + (lane & 15);
  #pragma unroll
  for (int m = 0; m < 4; ++m)
    #pragma unroll
    for (int n = 0; n < 4; ++n)
      #pragma unroll
      for (int j = 0; j < 4; ++j) {
        int r = rb + m * 16 + j, c = cb + n * 16;
        if (OUT_BF16)
          ((u16*)Cv)[(size_t)b * sC + (size_t)r * ldc + c] = f2bf(acc[m][n][j]);
        else
          ((float*)Cv)[(size_t)b * sC + (size_t)r * ldc + c] = acc[m][n][j];
      }
}

// ---------------- split-precision NT GEMM for scores (R13-measured winner) ----------------
__global__ __launch_bounds__(256, 2)
void k_gemm_nt_split(const u16* __restrict__ Ah, const u16* __restrict__ Al,
                     const u16* __restrict__ Bh, const u16* __restrict__ Bl,
                     float* __restrict__ C, int K, int ldc, size_t sAB, size_t sC, int tilesN)
{
  __shared__ __align__(16) u16 Ahs[128 * 64];
  __shared__ __align__(16) u16 Als[128 * 64];
  __shared__ __align__(16) u16 Bhs[128 * 64];
  __shared__ __align__(16) u16 Bls[128 * 64];
  const int bx = blockIdx.x;
  const int tm = bx / tilesN, tn = bx % tilesN;
  const int b = blockIdx.y;
  const size_t aoff = (size_t)b * sAB + (size_t)tm * 128 * K;
  const size_t boff = (size_t)b * sAB + (size_t)tn * 128 * K;
  const int tid = threadIdx.x;
  const int lane = tid & 63, wv = tid >> 6;
  const int wm = wv >> 1, wn = wv & 1;
  const int srow = tid >> 3;
  const int scol = (tid & 7) * 8;
  const int scolswz = swz(srow, scol);
  f32x4 acc[4][4] = {};
  for (int k0 = 0; k0 < K; k0 += 64) {
    #pragma unroll
    for (int i = 0; i < 4; ++i) {
      int row = i * 32 + srow;
      size_t ga = aoff + (size_t)row * K + k0 + scolswz;
      size_t gb = boff + (size_t)row * K + k0 + scolswz;
      int ls = row * 64 + scol;
      gload16(Ah + ga, &Ahs[ls]);
      gload16(Al + ga, &Als[ls]);
      gload16(Bh + gb, &Bhs[ls]);
      gload16(Bl + gb, &Bls[ls]);
    }
    __syncthreads();
    const int hi8 = (lane >> 4) * 8;
    #pragma unroll
    for (int kk = 0; kk < 64; kk += 32) {
      bf16x8 ah[4], al[4], bh[4], bl[4];
      #pragma unroll
      for (int m = 0; m < 4; ++m) {
        int rr = wm * 64 + m * 16 + (lane & 15);
        int off = rr * 64 + swz(rr, kk + hi8);
        ah[m] = *(const bf16x8*)&Ahs[off];
        al[m] = *(const bf16x8*)&Als[off];
      }
      #pragma unroll
      for (int n = 0; n < 4; ++n) {
        int rr = wn * 64 + n * 16 + (lane & 15);
        int off = rr * 64 + swz(rr, kk + hi8);
        bh[n] = *(const bf16x8*)&Bhs[off];
        bl[n] = *(const bf16x8*)&Bls[off];
      }
      #pragma unroll
      for (int m = 0; m < 4; ++m)
        #pragma unroll
        for (int n = 0; n < 4; ++n) {
          acc[m][n] = __builtin_amdgcn_mfma_f32_16x16x32_bf16(ah[m], bh[n], acc[m][n], 0, 0, 0);
          acc[m][n] = __builtin_amdgcn_mfma_f32_16x16x32_bf16(ah[m], bl[n], acc[m][n], 0, 0, 0);
          acc[m][n] = __builtin_amdgcn_mfma_f32_16x16x32_bf16(al[m], bh[n], acc[m][n], 0, 0, 0);
        }
    }
    __syncthreads();
  }
  const int rb = tm * 128 + wm * 64 + ((lane >> 4) << 2);
  const int cb = tn * 128 + wn * 64 + (lane & 15);
  #pragma unroll
  for (int m = 0; m < 4; ++m)
    #pragma unroll
    for (int n = 0; n < 4; ++n)
      #pragma unroll
      for (int j = 0; j < 4; ++j) {
        int r = rb + m * 16 + j, c = cb + n * 16;
        C[(size_t)b * sC + (size_t)r * ldc + c] = acc[m][n][j];
      }
}

// ---------------- masked row softmax ----------------
__global__ __launch_bounds__(256)
void k_row_softmax(const float* __restrict__ a, u16* __restrict__ P,
                   const int* __restrict__ m1, const int* __restrict__ m2)
{
  const int row = blockIdx.x, b = blockIdx.y;
  const float* ar = a + ((size_t)b * L + row) * L;
  const int tid = threadIdx.x, lane = tid & 63, wv = tid >> 6;
  __shared__ float redm[4], reds[4];
  float4 v = ((const float4*)ar)[tid];
  int4 mv = ((const int4*)(m2 + (size_t)b * L))[tid];
  const int mr = m1[(size_t)b * L + row];
  float x0 = v.x + (float)(1 - mr * mv.x) * (-1e29f);
  float x1 = v.y + (float)(1 - mr * mv.y) * (-1e29f);
  float x2 = v.z + (float)(1 - mr * mv.z) * (-1e29f);
  float x3 = v.w + (float)(1 - mr * mv.w) * (-1e29f);
  float mx = fmaxf(fmaxf(x0, x1), fmaxf(x2, x3));
  #pragma unroll
  for (int o = 32; o > 0; o >>= 1) mx = fmaxf(mx, __shfl_xor(mx, o));
  if (lane == 0) redm[wv] = mx;
  __syncthreads();
  mx = fmaxf(fmaxf(redm[0], redm[1]), fmaxf(redm[2], redm[3]));
  float e0 = __expf(x0 - mx), e1 = __expf(x1 - mx), e2 = __expf(x2 - mx), e3 = __expf(x3 - mx);
  float s4 = e0 + e1 + e2 + e3;
  #pragma unroll
  for (int o = 32; o > 0; o >>= 1) s4 += __shfl_xor(s4, o);
  if (lane == 0) reds[wv] = s4;
  __syncthreads();
  float inv = 1.0f / (reds[0] + reds[1] + reds[2] + reds[3]);
  ushort4 o;
  o.x = f2bf(e0 * inv); o.y = f2bf(e1 * inv); o.z = f2bf(e2 * inv); o.w = f2bf(e3 * inv);
  ((ushort4*)(P + ((size_t)b * L + row) * L))[tid] = o;
}

// ---------------- masked column softmax: P2[t][s] = softmax_s(a[s][t]) ----------------
__global__ __launch_bounds__(256)
void k_col_softmax(const float* __restrict__ a, u16* __restrict__ P,
                   const int* __restrict__ mrow, const int* __restrict__ mcol)
{
  __shared__ float mred[4][64], lred[4][64];
  __shared__ float Mc[64], Li[64];
  __shared__ u16 T[64][68];
  const int b = blockIdx.y;
  const int c0 = blockIdx.x * 64;
  const int tid = threadIdx.x;
  const int cl = tid & 63;
  const int qr = tid >> 6;
  const int c = c0 + cl;
  const float* ab = a + (size_t)b * L * L;
  const int mc = mcol[(size_t)b * L + c];
  const int* msk = mrow + (size_t)b * L;
  float m = -3.0e38f, l = 0.0f;
  for (int r = qr * 256; r < qr * 256 + 256; ++r) {
    float x = ab[(size_t)r * L + c] + (float)(1 - mc * msk[r]) * (-1e29f);
    float mn = fmaxf(m, x);
    l = l * __expf(m - mn) + __expf(x - mn);
    m = mn;
  }
  mred[qr][cl] = m; lred[qr][cl] = l;
  __syncthreads();
  if (tid < 64) {
    float M = fmaxf(fmaxf(mred[0][tid], mred[1][tid]), fmaxf(mred[2][tid], mred[3][tid]));
    float Lt = lred[0][tid] * __expf(mred[0][tid] - M) + lred[1][tid] * __expf(mred[1][tid] - M)
             + lred[2][tid] * __expf(mred[2][tid] - M) + lred[3][tid] * __expf(mred[3][tid] - M);
    Mc[tid] = M; Li[tid] = 1.0f / Lt;
  }
  __syncthreads();
  const float M = Mc[cl], Linv = Li[cl];
  u16* Pb = P + (size_t)b * L * L;
  const int tl = tid >> 2, sc = (tid & 3) * 16;
  for (int ch = 0; ch < 16; ++ch) {
    #pragma unroll
    for (int rs = 0; rs < 16; ++rs) {
      int r = ch * 64 + qr * 16 + rs;
      float x = ab[(size_t)r * L + c] + (float)(1 - mc * msk[r]) * (-1e29f);
      T[cl][qr * 16 + rs] = f2bf(__expf(x - M) * Linv);
    }
    __syncthreads();
    ushort4* d4 = (ushort4*)(Pb + (size_t)(c0 + tl) * L + ch * 64 + sc);
    #pragma unroll
    for (int jj = 0; jj < 4; ++jj) {
      ushort4 v;
      v.x = T[tl][sc + jj * 4 + 0]; v.y = T[tl][sc + jj * 4 + 1];
      v.z = T[tl][sc + jj * 4 + 2]; v.w = T[tl][sc + jj * 4 + 3];
      d4[jj] = v;
    }
    __syncthreads();
  }
}

// ---------------- heuristic v7c: m97-structure GEMM + lean epilogue, 5 blocks/CU ----------------
// Single-acc GEMM: A = [X|Y|XY|XMY] (M=16384, K=4096), B = wcat (N=2048 interleaved).
// K-loop = R13-proven. (256,5): LDS 32KB allows 5 blocks/CU (160/32); VGPR 60 fits.
__global__ __launch_bounds__(256, 5)
void k_heur5(const u16* __restrict__ X, const u16* __restrict__ Y,
             const u16* __restrict__ XY, const u16* __restrict__ XMY,
             const u16* __restrict__ Wc,
             const float* __restrict__ br, const float* __restrict__ bg,
             const u16* __restrict__ Xf, float* __restrict__ out)
{
  __shared__ __align__(16) u16 As[128 * 64];
  __shared__ __align__(16) u16 Bs[128 * 64];
  const int bx = blockIdx.x;
  const int xcd = bx & 7, li = bx >> 3;
  const int tn = li & 15, tm = xcd * 16 + (li >> 4);   // 16 tn x 128 tm
  const size_t rowBase = (size_t)tm * 128;
  const int colBase = tn * 128;                        // interleaved col base
  const u16* Bp = Wc + (size_t)colBase * KH;
  const int tid = threadIdx.x;
  const int lane = tid & 63, wv = tid >> 6;
  const int wm = wv >> 1, wn = wv & 1;
  const int srow = tid >> 3;
  const int scol = (tid & 7) * 8;
  const int scolswz = swz(srow, scol);
  f32x4 acc[4][4] = {};
  for (int k0 = 0; k0 < KH; k0 += 64) {
    const u16* ap = (k0 < 2048) ? (k0 < 1024 ? X : Y) : (k0 < 3072 ? XY : XMY);
    const int kc = k0 & 1023;
    #pragma unroll
    for (int i = 0; i < 4; ++i) {
      int row = i * 32 + srow;
      gload16(ap + (rowBase + row) * (size_t)D + kc + scolswz, &As[row * 64 + scol]);
    }
    #pragma unroll
    for (int i = 0; i < 4; ++i) {
      int row = i * 32 + srow;
      gload16(Bp + (size_t)row * KH + k0 + scolswz, &Bs[row * 64 + scol]);
    }
    __syncthreads();
    const int hi8 = (lane >> 4) * 8;
    #pragma unroll
    for (int kk = 0; kk < 64; kk += 32) {
      bf16x8 af[4], bfv[4];
      #pragma unroll
      for (int m = 0; m < 4; ++m) {
        int rr = wm * 64 + m * 16 + (lane & 15);
        af[m] = *(const bf16x8*)&As[rr * 64 + swz(rr, kk + hi8)];
      }
      #pragma unroll
      for (int n = 0; n < 4; ++n) {
        int rr = wn * 64 + n * 16 + (lane & 15);
        bfv[n] = *(const bf16x8*)&Bs[rr * 64 + swz(rr, kk + hi8)];
      }
      #pragma unroll
      for (int m = 0; m < 4; ++m)
        #pragma unroll
        for (int n = 0; n < 4; ++n)
          acc[m][n] = __builtin_amdgcn_mfma_f32_16x16x32_bf16(af[m], bfv[n], acc[m][n], 0, 0, 0);
    }
    __syncthreads();
  }
  // lean epilogue: parity j-split + one shfl per (m,n,j) + fast tanh
  const int rb = wm * 64 + ((lane >> 4) << 2);
  const int cbl = wn * 64 + (lane & 15);
  const int odd = lane & 1;
  #pragma unroll
  for (int m = 0; m < 4; ++m)
    #pragma unroll
    for (int n = 0; n < 4; ++n) {
      int ncol = colBase + cbl + n * 16;
      int cc = ncol >> 1;
      float brc = br[cc], bgc = bg[cc];
      #pragma unroll
      for (int j = 0; j < 2; ++j) {
        int jj = odd ? (j + 2) : j;
        float own  = odd ? acc[m][n][j + 2] : acc[m][n][j];
        float send = odd ? acc[m][n][j]     : acc[m][n][j + 2];
        float recv = __shfl_xor(send, 1);
        float r  = odd ? recv : own;
        float g2 = odd ? own : recv;
        r += brc; g2 += bgc;
        float z = 0.79788456080286535588f * (r + 0.044715f * r * r * r);
        float th = 1.0f - 2.0f / (__expf(2.0f * z) + 1.0f);
        float gl = 0.5f * r * (1.0f + th);
        float sg = 1.0f / (1.0f + __expf(-g2));
        size_t row = rowBase + rb + m * 16 + jj;
        float xv = bf2f(Xf[row * (size_t)D + cc]);
        out[row * (size_t)D + cc] = sg * gl + (1.0f - sg) * xv;
      }
    }
}

extern "C" void kernel_launch(void* const* d_in, const int* in_sizes, int n_in,
                              void* d_out, int out_size, void* d_ws, size_t ws_size,
                              hipStream_t stream)
{
  (void)in_sizes; (void)n_in; (void)out_size; (void)ws_size;
  const float* s    = (const float*)d_in[0];
  const float* q    = (const float*)d_in[1];
  const float* w_r  = (const float*)d_in[2];
  const float* b_r  = (const float*)d_in[3];
  const float* w_g  = (const float*)d_in[4];
  const float* b_g  = (const float*)d_in[5];
  const int* s_mask = (const int*)d_in[6];
  const int* q_mask = (const int*)d_in[7];
  float* out = (float*)d_out;

  const size_t SQ = (size_t)Bb * L * D;   // 16M elems
  const size_t W  = (size_t)D * KH;       // 4M elems
  const size_t S1 = (size_t)L * D;        // per-batch stride (1M)

  char* p = (char*)d_ws;
  u16* s_bf  = (u16*)p; p += SQ * 2;      // s hi
  u16* q_bf  = (u16*)p; p += SQ * 2;      // q hi
  u16* buf1  = (u16*)p; p += SQ * 2;      // s_lo -> sT -> xy
  u16* buf2  = (u16*)p; p += SQ * 2;      // q_lo -> qT -> xmy
  u16* b_bf  = (u16*)p; p += SQ * 2;
  u16* c_bf  = (u16*)p; p += SQ * 2;
  u16* wcat  = (u16*)p; p += 2 * W * 2;   // interleaved Wr/Wg bf16 [2048][4096]

  // scratch carved out of d_out (dead before the final heuristic writes)
  float* a  = out;                        // [B][L][L] f32 = 64 MB
  u16*   P1 = (u16*)(out + SQ);           // bf16 32 MB
  u16*   P2 = (u16*)(out + SQ + SQ / 2);  // bf16 32 MB

  dim3 blk(256);
  k_cast_split<<<4096, blk, 0, stream>>>(s, s_bf, buf1, (int)(SQ / 4));
  k_cast_split<<<4096, blk, 0, stream>>>(q, q_bf, buf2, (int)(SQ / 4));
  k_wcat<<<4096, blk, 0, stream>>>(w_r, w_g, wcat, (int)(2 * W / 4));

  // a = s q^T (split precision); a^T handled by col-softmax
  dim3 ggrid(64, Bb);
  k_gemm_nt_split<<<ggrid, blk, 0, stream>>>(s_bf, buf1, q_bf, buf2, a, D, L, S1, (size_t)L * L, 8);
  k_row_softmax<<<dim3(L, Bb), blk, 0, stream>>>(a, P1, s_mask, q_mask);
  k_col_softmax<<<dim3(L / 64, Bb), blk, 0, stream>>>(a, P2, s_mask, q_mask);

  // s_lo/q_lo dead; reuse buf1/buf2 as transposed s/q (from bf16 sources)
  dim3 tgrid(D / 32, L / 32, Bb), tblk(32, 8);
  k_transpose_bf16<<<tgrid, tblk, 0, stream>>>(s_bf, buf1);   // sT
  k_transpose_bf16<<<tgrid, tblk, 0, stream>>>(q_bf, buf2);   // qT

  // b = P1 @ q (via qT), c = P2 @ s (via sT)
  k_gemm_nt<1><<<ggrid, blk, 0, stream>>>(P1, buf2, b_bf, L, D, (size_t)L * L, S1, S1, 8);
  k_gemm_nt<1><<<ggrid, blk, 0, stream>>>(P2, buf1, c_bf, L, D, (size_t)L * L, S1, S1, 8);

  // s side: precompute features (sT/qT dead now), then GEMM + lean epilogue
  k_feat<<<2048, blk, 0, stream>>>(s_bf, b_bf, buf1, buf2, (int)(SQ / 8));
  k_heur5<<<2048, blk, 0, stream>>>(s_bf, b_bf, buf1, buf2, wcat, b_r, b_g, s_bf, out);

  // q side
  k_feat<<<2048, blk, 0, stream>>>(q_bf, c_bf, buf1, buf2, (int)(SQ / 8));
  k_heur5<<<2048, blk, 0, stream>>>(q_bf, c_bf, buf1, buf2, wcat, b_r, b_g, q_bf, out + SQ);
}

// Round 16
// 932.862 us; speedup vs baseline: 1.8394x; 1.8394x over previous
//
#include <hip/hip_runtime.h>
#include <hip/hip_bf16.h>
#include <math.h>

#define DEVI static __device__ __forceinline__

typedef unsigned short u16;
typedef unsigned int u32;
typedef __bf16 bf16_t;
typedef bf16_t bf16x8 __attribute__((ext_vector_type(8)));
typedef float f32x4 __attribute__((ext_vector_type(4)));

static constexpr int Bb = 16;     // batch
static constexpr int L  = 1024;   // seq len
static constexpr int D  = 1024;   // 2H
static constexpr int KH = 4096;   // heuristic K = 8H

DEVI u16 f2bf(float f) {
  union { float f; u32 u; } v; v.f = f;
  u32 r = v.u + 0x7FFFu + ((v.u >> 16) & 1u);
  return (u16)(r >> 16);
}

DEVI float bf2f(u16 b) {
  union { u32 u; float f; } v; v.u = ((u32)b) << 16;
  return v.f;
}

DEVI void gload16(const void* g, void* l) {
  __builtin_amdgcn_global_load_lds((const __attribute__((address_space(1))) u32*)g,
                                   (__attribute__((address_space(3))) u32*)l,
                                   16, 0, 0);
}

// element-unit XOR swizzle within a 64-wide bf16 LDS row (T2):
DEVI int swz(int row, int col) { return col ^ ((row & 7) << 3); }

// ---------------- split cast: f32 -> hi bf16 + lo bf16 (residual) ----------------
__global__ void k_cast_split(const float* __restrict__ in, u16* __restrict__ hi,
                             u16* __restrict__ lo, int n4) {
  int i = blockIdx.x * blockDim.x + threadIdx.x;
  int stride = gridDim.x * blockDim.x;
  for (; i < n4; i += stride) {
    float4 v = ((const float4*)in)[i];
    ushort4 h, l;
    h.x = f2bf(v.x); h.y = f2bf(v.y); h.z = f2bf(v.z); h.w = f2bf(v.w);
    l.x = f2bf(v.x - bf2f(h.x));
    l.y = f2bf(v.y - bf2f(h.y));
    l.z = f2bf(v.z - bf2f(h.z));
    l.w = f2bf(v.w - bf2f(h.w));
    ((ushort4*)hi)[i] = h;
    ((ushort4*)lo)[i] = l;
  }
}

// ---------------- interleave weights: wcat[2j]=w_r[j], wcat[2j+1]=w_g[j] (bf16) ----------------
__global__ void k_wcat(const float* __restrict__ wr, const float* __restrict__ wg,
                       u16* __restrict__ wcat, int n4) {
  int i = blockIdx.x * blockDim.x + threadIdx.x;
  int stride = gridDim.x * blockDim.x;
  for (; i < n4; i += stride) {
    int j = i >> 10;              // interleaved row (2048)
    int c4 = i & 1023;            // float4 chunk within row (4096/4)
    const float* src = ((j & 1) ? wg : wr) + (size_t)(j >> 1) * 4096 + c4 * 4;
    float4 v = *(const float4*)src;
    ushort4 o;
    o.x = f2bf(v.x); o.y = f2bf(v.y); o.z = f2bf(v.z); o.w = f2bf(v.w);
    ((ushort4*)wcat)[i] = o;
  }
}

// ---------------- features: xy = x*y, xmy = x-y (bf16 in, bf16 out) ----------------
__global__ void k_feat(const u16* __restrict__ x, const u16* __restrict__ y,
                       u16* __restrict__ xy, u16* __restrict__ xmy, int n8) {
  int i = blockIdx.x * blockDim.x + threadIdx.x;
  int stride = gridDim.x * blockDim.x;
  for (; i < n8; i += stride) {
    bf16x8 xv = ((const bf16x8*)x)[i];
    bf16x8 yv = ((const bf16x8*)y)[i];
    bf16x8 p, d;
    #pragma unroll
    for (int j = 0; j < 8; ++j) {
      float xf = (float)xv[j], yf = (float)yv[j];
      p[j] = (bf16_t)(xf * yf);
      d[j] = (bf16_t)(xf - yf);
    }
    ((bf16x8*)xy)[i] = p;
    ((bf16x8*)xmy)[i] = d;
  }
}

// ---------------- transpose (bf16 in, bf16 out): [B][L][D] -> [B][D][L] ----------------
__global__ __launch_bounds__(256)
void k_transpose_bf16(const u16* __restrict__ in, u16* __restrict__ out) {
  __shared__ u16 tile[32][33];
  int b = blockIdx.z;
  int d0 = blockIdx.x * 32;
  int l0 = blockIdx.y * 32;
  const u16* ip = in + (size_t)b * L * D;
  u16* op = out + (size_t)b * L * D;
  int tx = threadIdx.x, ty = threadIdx.y;
  #pragma unroll
  for (int j = 0; j < 4; ++j)
    tile[ty + 8 * j][tx] = ip[(size_t)(l0 + ty + 8 * j) * D + d0 + tx];
  __syncthreads();
  #pragma unroll
  for (int j = 0; j < 4; ++j)
    op[(size_t)(d0 + ty + 8 * j) * L + l0 + tx] = tile[tx][ty + 8 * j];
}

// ---------------- NT GEMM: C[m][n] = sum_k A[m][k] * B[n][k] (PV GEMMs) ----------------
template<int OUT_BF16>
__global__ __launch_bounds__(256, 4)
void k_gemm_nt(const u16* __restrict__ A, const u16* __restrict__ Bm, void* __restrict__ Cv,
               int K, int ldc, size_t sA, size_t sB, size_t sC, int tilesN)
{
  __shared__ __align__(16) u16 As[128 * 64];
  __shared__ __align__(16) u16 Bs[128 * 64];
  const int bx = blockIdx.x;
  const int tm = bx / tilesN, tn = bx % tilesN;
  const int b = blockIdx.y;
  const u16* Ap = A + (size_t)b * sA + (size_t)tm * 128 * K;
  const u16* Bp = Bm + (size_t)b * sB + (size_t)tn * 128 * K;
  const int tid = threadIdx.x;
  const int lane = tid & 63, wv = tid >> 6;
  const int wm = wv >> 1, wn = wv & 1;
  const int srow = tid >> 3;
  const int scol = (tid & 7) * 8;
  const int scolswz = swz(srow, scol);
  f32x4 acc[4][4] = {};
  for (int k0 = 0; k0 < K; k0 += 64) {
    #pragma unroll
    for (int i = 0; i < 4; ++i) {
      int row = i * 32 + srow;
      gload16(Ap + (size_t)row * K + k0 + scolswz, &As[row * 64 + scol]);
    }
    #pragma unroll
    for (int i = 0; i < 4; ++i) {
      int row = i * 32 + srow;
      gload16(Bp + (size_t)row * K + k0 + scolswz, &Bs[row * 64 + scol]);
    }
    __syncthreads();
    const int hi8 = (lane >> 4) * 8;
    #pragma unroll
    for (int kk = 0; kk < 64; kk += 32) {
      bf16x8 af[4], bfv[4];
      #pragma unroll
      for (int m = 0; m < 4; ++m) {
        int rr = wm * 64 + m * 16 + (lane & 15);
        af[m] = *(const bf16x8*)&As[rr * 64 + swz(rr, kk + hi8)];
      }
      #pragma unroll
      for (int n = 0; n < 4; ++n) {
        int rr = wn * 64 + n * 16 + (lane & 15);
        bfv[n] = *(const bf16x8*)&Bs[rr * 64 + swz(rr, kk + hi8)];
      }
      #pragma unroll
      for (int m = 0; m < 4; ++m)
        #pragma unroll
        for (int n = 0; n < 4; ++n)
          acc[m][n] = __builtin_amdgcn_mfma_f32_16x16x32_bf16(af[m], bfv[n], acc[m][n], 0, 0, 0);
    }
    __syncthreads();
  }
  const int rb = tm * 128 + wm * 64 + ((lane >> 4) << 2);
  const int cb = tn * 128 + wn * 64 + (lane & 15);
  #pragma unroll
  for (int m = 0; m < 4; ++m)
    #pragma unroll
    for (int n = 0; n < 4; ++n)
      #pragma unroll
      for (int j = 0; j < 4; ++j) {
        int r = rb + m * 16 + j, c = cb + n * 16;
        if (OUT_BF16)
          ((u16*)Cv)[(size_t)b * sC + (size_t)r * ldc + c] = f2bf(acc[m][n][j]);
        else
          ((float*)Cv)[(size_t)b * sC + (size_t)r * ldc + c] = acc[m][n][j];
      }
}

// ---------------- split-precision NT GEMM for scores (measured winner) ----------------
__global__ __launch_bounds__(256, 2)
void k_gemm_nt_split(const u16* __restrict__ Ah, const u16* __restrict__ Al,
                     const u16* __restrict__ Bh, const u16* __restrict__ Bl,
                     float* __restrict__ C, int K, int ldc, size_t sAB, size_t sC, int tilesN)
{
  __shared__ __align__(16) u16 Ahs[128 * 64];
  __shared__ __align__(16) u16 Als[128 * 64];
  __shared__ __align__(16) u16 Bhs[128 * 64];
  __shared__ __align__(16) u16 Bls[128 * 64];
  const int bx = blockIdx.x;
  const int tm = bx / tilesN, tn = bx % tilesN;
  const int b = blockIdx.y;
  const size_t aoff = (size_t)b * sAB + (size_t)tm * 128 * K;
  const size_t boff = (size_t)b * sAB + (size_t)tn * 128 * K;
  const int tid = threadIdx.x;
  const int lane = tid & 63, wv = tid >> 6;
  const int wm = wv >> 1, wn = wv & 1;
  const int srow = tid >> 3;
  const int scol = (tid & 7) * 8;
  const int scolswz = swz(srow, scol);
  f32x4 acc[4][4] = {};
  for (int k0 = 0; k0 < K; k0 += 64) {
    #pragma unroll
    for (int i = 0; i < 4; ++i) {
      int row = i * 32 + srow;
      size_t ga = aoff + (size_t)row * K + k0 + scolswz;
      size_t gb = boff + (size_t)row * K + k0 + scolswz;
      int ls = row * 64 + scol;
      gload16(Ah + ga, &Ahs[ls]);
      gload16(Al + ga, &Als[ls]);
      gload16(Bh + gb, &Bhs[ls]);
      gload16(Bl + gb, &Bls[ls]);
    }
    __syncthreads();
    const int hi8 = (lane >> 4) * 8;
    #pragma unroll
    for (int kk = 0; kk < 64; kk += 32) {
      bf16x8 ah[4], al[4], bh[4], bl[4];
      #pragma unroll
      for (int m = 0; m < 4; ++m) {
        int rr = wm * 64 + m * 16 + (lane & 15);
        int off = rr * 64 + swz(rr, kk + hi8);
        ah[m] = *(const bf16x8*)&Ahs[off];
        al[m] = *(const bf16x8*)&Als[off];
      }
      #pragma unroll
      for (int n = 0; n < 4; ++n) {
        int rr = wn * 64 + n * 16 + (lane & 15);
        int off = rr * 64 + swz(rr, kk + hi8);
        bh[n] = *(const bf16x8*)&Bhs[off];
        bl[n] = *(const bf16x8*)&Bls[off];
      }
      #pragma unroll
      for (int m = 0; m < 4; ++m)
        #pragma unroll
        for (int n = 0; n < 4; ++n) {
          acc[m][n] = __builtin_amdgcn_mfma_f32_16x16x32_bf16(ah[m], bh[n], acc[m][n], 0, 0, 0);
          acc[m][n] = __builtin_amdgcn_mfma_f32_16x16x32_bf16(ah[m], bl[n], acc[m][n], 0, 0, 0);
          acc[m][n] = __builtin_amdgcn_mfma_f32_16x16x32_bf16(al[m], bh[n], acc[m][n], 0, 0, 0);
        }
    }
    __syncthreads();
  }
  const int rb = tm * 128 + wm * 64 + ((lane >> 4) << 2);
  const int cb = tn * 128 + wn * 64 + (lane & 15);
  #pragma unroll
  for (int m = 0; m < 4; ++m)
    #pragma unroll
    for (int n = 0; n < 4; ++n)
      #pragma unroll
      for (int j = 0; j < 4; ++j) {
        int r = rb + m * 16 + j, c = cb + n * 16;
        C[(size_t)b * sC + (size_t)r * ldc + c] = acc[m][n][j];
      }
}

// ---------------- masked row softmax ----------------
__global__ __launch_bounds__(256)
void k_row_softmax(const float* __restrict__ a, u16* __restrict__ P,
                   const int* __restrict__ m1, const int* __restrict__ m2)
{
  const int row = blockIdx.x, b = blockIdx.y;
  const float* ar = a + ((size_t)b * L + row) * L;
  const int tid = threadIdx.x, lane = tid & 63, wv = tid >> 6;
  __shared__ float redm[4], reds[4];
  float4 v = ((const float4*)ar)[tid];
  int4 mv = ((const int4*)(m2 + (size_t)b * L))[tid];
  const int mr = m1[(size_t)b * L + row];
  float x0 = v.x + (float)(1 - mr * mv.x) * (-1e29f);
  float x1 = v.y + (float)(1 - mr * mv.y) * (-1e29f);
  float x2 = v.z + (float)(1 - mr * mv.z) * (-1e29f);
  float x3 = v.w + (float)(1 - mr * mv.w) * (-1e29f);
  float mx = fmaxf(fmaxf(x0, x1), fmaxf(x2, x3));
  #pragma unroll
  for (int o = 32; o > 0; o >>= 1) mx = fmaxf(mx, __shfl_xor(mx, o));
  if (lane == 0) redm[wv] = mx;
  __syncthreads();
  mx = fmaxf(fmaxf(redm[0], redm[1]), fmaxf(redm[2], redm[3]));
  float e0 = __expf(x0 - mx), e1 = __expf(x1 - mx), e2 = __expf(x2 - mx), e3 = __expf(x3 - mx);
  float s4 = e0 + e1 + e2 + e3;
  #pragma unroll
  for (int o = 32; o > 0; o >>= 1) s4 += __shfl_xor(s4, o);
  if (lane == 0) reds[wv] = s4;
  __syncthreads();
  float inv = 1.0f / (reds[0] + reds[1] + reds[2] + reds[3]);
  ushort4 o;
  o.x = f2bf(e0 * inv); o.y = f2bf(e1 * inv); o.z = f2bf(e2 * inv); o.w = f2bf(e3 * inv);
  ((ushort4*)(P + ((size_t)b * L + row) * L))[tid] = o;
}

// ---------------- masked column softmax: P2[t][s] = softmax_s(a[s][t]) ----------------
__global__ __launch_bounds__(256)
void k_col_softmax(const float* __restrict__ a, u16* __restrict__ P,
                   const int* __restrict__ mrow, const int* __restrict__ mcol)
{
  __shared__ float mred[4][64], lred[4][64];
  __shared__ float Mc[64], Li[64];
  __shared__ u16 T[64][68];
  const int b = blockIdx.y;
  const int c0 = blockIdx.x * 64;
  const int tid = threadIdx.x;
  const int cl = tid & 63;
  const int qr = tid >> 6;
  const int c = c0 + cl;
  const float* ab = a + (size_t)b * L * L;
  const int mc = mcol[(size_t)b * L + c];
  const int* msk = mrow + (size_t)b * L;
  float m = -3.0e38f, l = 0.0f;
  for (int r = qr * 256; r < qr * 256 + 256; ++r) {
    float x = ab[(size_t)r * L + c] + (float)(1 - mc * msk[r]) * (-1e29f);
    float mn = fmaxf(m, x);
    l = l * __expf(m - mn) + __expf(x - mn);
    m = mn;
  }
  mred[qr][cl] = m; lred[qr][cl] = l;
  __syncthreads();
  if (tid < 64) {
    float M = fmaxf(fmaxf(mred[0][tid], mred[1][tid]), fmaxf(mred[2][tid], mred[3][tid]));
    float Lt = lred[0][tid] * __expf(mred[0][tid] - M) + lred[1][tid] * __expf(mred[1][tid] - M)
             + lred[2][tid] * __expf(mred[2][tid] - M) + lred[3][tid] * __expf(mred[3][tid] - M);
    Mc[tid] = M; Li[tid] = 1.0f / Lt;
  }
  __syncthreads();
  const float M = Mc[cl], Linv = Li[cl];
  u16* Pb = P + (size_t)b * L * L;
  const int tl = tid >> 2, sc = (tid & 3) * 16;
  for (int ch = 0; ch < 16; ++ch) {
    #pragma unroll
    for (int rs = 0; rs < 16; ++rs) {
      int r = ch * 64 + qr * 16 + rs;
      float x = ab[(size_t)r * L + c] + (float)(1 - mc * msk[r]) * (-1e29f);
      T[cl][qr * 16 + rs] = f2bf(__expf(x - M) * Linv);
    }
    __syncthreads();
    ushort4* d4 = (ushort4*)(Pb + (size_t)(c0 + tl) * L + ch * 64 + sc);
    #pragma unroll
    for (int jj = 0; jj < 4; ++jj) {
      ushort4 v;
      v.x = T[tl][sc + jj * 4 + 0]; v.y = T[tl][sc + jj * 4 + 1];
      v.z = T[tl][sc + jj * 4 + 2]; v.w = T[tl][sc + jj * 4 + 3];
      d4[jj] = v;
    }
    __syncthreads();
  }
}

// ---------------- heuristic v7b: m97-structure GEMM + lean epilogue, (256,4) ----------------
// NOTE: (256,5) spills acc to scratch (R15: VGPR 60->48, WRITE 66MB->1.1GB, 2.6x slower).
// (256,4) is the measured optimum: 4 blocks/CU, 0 spill, MfmaUtil ~50%.
__global__ __launch_bounds__(256, 4)
void k_heur5(const u16* __restrict__ X, const u16* __restrict__ Y,
             const u16* __restrict__ XY, const u16* __restrict__ XMY,
             const u16* __restrict__ Wc,
             const float* __restrict__ br, const float* __restrict__ bg,
             const u16* __restrict__ Xf, float* __restrict__ out)
{
  __shared__ __align__(16) u16 As[128 * 64];
  __shared__ __align__(16) u16 Bs[128 * 64];
  const int bx = blockIdx.x;
  const int xcd = bx & 7, li = bx >> 3;
  const int tn = li & 15, tm = xcd * 16 + (li >> 4);   // 16 tn x 128 tm
  const size_t rowBase = (size_t)tm * 128;
  const int colBase = tn * 128;                        // interleaved col base
  const u16* Bp = Wc + (size_t)colBase * KH;
  const int tid = threadIdx.x;
  const int lane = tid & 63, wv = tid >> 6;
  const int wm = wv >> 1, wn = wv & 1;
  const int srow = tid >> 3;
  const int scol = (tid & 7) * 8;
  const int scolswz = swz(srow, scol);
  f32x4 acc[4][4] = {};
  for (int k0 = 0; k0 < KH; k0 += 64) {
    const u16* ap = (k0 < 2048) ? (k0 < 1024 ? X : Y) : (k0 < 3072 ? XY : XMY);
    const int kc = k0 & 1023;
    #pragma unroll
    for (int i = 0; i < 4; ++i) {
      int row = i * 32 + srow;
      gload16(ap + (rowBase + row) * (size_t)D + kc + scolswz, &As[row * 64 + scol]);
    }
    #pragma unroll
    for (int i = 0; i < 4; ++i) {
      int row = i * 32 + srow;
      gload16(Bp + (size_t)row * KH + k0 + scolswz, &Bs[row * 64 + scol]);
    }
    __syncthreads();
    const int hi8 = (lane >> 4) * 8;
    #pragma unroll
    for (int kk = 0; kk < 64; kk += 32) {
      bf16x8 af[4], bfv[4];
      #pragma unroll
      for (int m = 0; m < 4; ++m) {
        int rr = wm * 64 + m * 16 + (lane & 15);
        af[m] = *(const bf16x8*)&As[rr * 64 + swz(rr, kk + hi8)];
      }
      #pragma unroll
      for (int n = 0; n < 4; ++n) {
        int rr = wn * 64 + n * 16 + (lane & 15);
        bfv[n] = *(const bf16x8*)&Bs[rr * 64 + swz(rr, kk + hi8)];
      }
      #pragma unroll
      for (int m = 0; m < 4; ++m)
        #pragma unroll
        for (int n = 0; n < 4; ++n)
          acc[m][n] = __builtin_amdgcn_mfma_f32_16x16x32_bf16(af[m], bfv[n], acc[m][n], 0, 0, 0);
    }
    __syncthreads();
  }
  // lean epilogue: parity j-split + one shfl per (m,n,j) + fast tanh
  const int rb = wm * 64 + ((lane >> 4) << 2);
  const int cbl = wn * 64 + (lane & 15);
  const int odd = lane & 1;
  #pragma unroll
  for (int m = 0; m < 4; ++m)
    #pragma unroll
    for (int n = 0; n < 4; ++n) {
      int ncol = colBase + cbl + n * 16;
      int cc = ncol >> 1;
      float brc = br[cc], bgc = bg[cc];
      #pragma unroll
      for (int j = 0; j < 2; ++j) {
        int jj = odd ? (j + 2) : j;
        float own  = odd ? acc[m][n][j + 2] : acc[m][n][j];
        float send = odd ? acc[m][n][j]     : acc[m][n][j + 2];
        float recv = __shfl_xor(send, 1);
        float r  = odd ? recv : own;
        float g2 = odd ? own : recv;
        r += brc; g2 += bgc;
        float z = 0.79788456080286535588f * (r + 0.044715f * r * r * r);
        float th = 1.0f - 2.0f / (__expf(2.0f * z) + 1.0f);
        float gl = 0.5f * r * (1.0f + th);
        float sg = 1.0f / (1.0f + __expf(-g2));
        size_t row = rowBase + rb + m * 16 + jj;
        float xv = bf2f(Xf[row * (size_t)D + cc]);
        out[row * (size_t)D + cc] = sg * gl + (1.0f - sg) * xv;
      }
    }
}

extern "C" void kernel_launch(void* const* d_in, const int* in_sizes, int n_in,
                              void* d_out, int out_size, void* d_ws, size_t ws_size,
                              hipStream_t stream)
{
  (void)in_sizes; (void)n_in; (void)out_size; (void)ws_size;
  const float* s    = (const float*)d_in[0];
  const float* q    = (const float*)d_in[1];
  const float* w_r  = (const float*)d_in[2];
  const float* b_r  = (const float*)d_in[3];
  const float* w_g  = (const float*)d_in[4];
  const float* b_g  = (const float*)d_in[5];
  const int* s_mask = (const int*)d_in[6];
  const int* q_mask = (const int*)d_in[7];
  float* out = (float*)d_out;

  const size_t SQ = (size_t)Bb * L * D;   // 16M elems
  const size_t W  = (size_t)D * KH;       // 4M elems
  const size_t S1 = (size_t)L * D;        // per-batch stride (1M)

  char* p = (char*)d_ws;
  u16* s_bf  = (u16*)p; p += SQ * 2;      // s hi
  u16* q_bf  = (u16*)p; p += SQ * 2;      // q hi
  u16* buf1  = (u16*)p; p += SQ * 2;      // s_lo -> sT -> xy
  u16* buf2  = (u16*)p; p += SQ * 2;      // q_lo -> qT -> xmy
  u16* b_bf  = (u16*)p; p += SQ * 2;
  u16* c_bf  = (u16*)p; p += SQ * 2;
  u16* wcat  = (u16*)p; p += 2 * W * 2;   // interleaved Wr/Wg bf16 [2048][4096]

  // scratch carved out of d_out (dead before the final heuristic writes)
  float* a  = out;                        // [B][L][L] f32 = 64 MB
  u16*   P1 = (u16*)(out + SQ);           // bf16 32 MB
  u16*   P2 = (u16*)(out + SQ + SQ / 2);  // bf16 32 MB

  dim3 blk(256);
  k_cast_split<<<4096, blk, 0, stream>>>(s, s_bf, buf1, (int)(SQ / 4));
  k_cast_split<<<4096, blk, 0, stream>>>(q, q_bf, buf2, (int)(SQ / 4));
  k_wcat<<<4096, blk, 0, stream>>>(w_r, w_g, wcat, (int)(2 * W / 4));

  // a = s q^T (split precision); a^T handled by col-softmax
  dim3 ggrid(64, Bb);
  k_gemm_nt_split<<<ggrid, blk, 0, stream>>>(s_bf, buf1, q_bf, buf2, a, D, L, S1, (size_t)L * L, 8);
  k_row_softmax<<<dim3(L, Bb), blk, 0, stream>>>(a, P1, s_mask, q_mask);
  k_col_softmax<<<dim3(L / 64, Bb), blk, 0, stream>>>(a, P2, s_mask, q_mask);

  // s_lo/q_lo dead; reuse buf1/buf2 as transposed s/q (from bf16 sources)
  dim3 tgrid(D / 32, L / 32, Bb), tblk(32, 8);
  k_transpose_bf16<<<tgrid, tblk, 0, stream>>>(s_bf, buf1);   // sT
  k_transpose_bf16<<<tgrid, tblk, 0, stream>>>(q_bf, buf2);   // qT

  // b = P1 @ q (via qT), c = P2 @ s (via sT)
  k_gemm_nt<1><<<ggrid, blk, 0, stream>>>(P1, buf2, b_bf, L, D, (size_t)L * L, S1, S1, 8);
  k_gemm_nt<1><<<ggrid, blk, 0, stream>>>(P2, buf1, c_bf, L, D, (size_t)L * L, S1, S1, 8);

  // s side: precompute features (sT/qT dead now), then GEMM + lean epilogue
  k_feat<<<2048, blk, 0, stream>>>(s_bf, b_bf, buf1, buf2, (int)(SQ / 8));
  k_heur5<<<2048, blk, 0, stream>>>(s_bf, b_bf, buf1, buf2, wcat, b_r, b_g, s_bf, out);

  // q side
  k_feat<<<2048, blk, 0, stream>>>(q_bf, c_bf, buf1, buf2, (int)(SQ / 8));
  k_heur5<<<2048, blk, 0, stream>>>(q_bf, c_bf, buf1, buf2, wcat, b_r, b_g, q_bf, out + SQ);
}